// Round 9
// baseline (302.886 us; speedup 1.0000x reference)
//
#include <hip/hip_runtime.h>

typedef unsigned short u16;
typedef unsigned int   u32;
typedef __attribute__((ext_vector_type(8))) short short8;   // 8 bf16 (4 VGPRs)
typedef __attribute__((ext_vector_type(4))) float f32x4;    // MFMA C/D

// ---- bf16 helpers (bf16 = top 16 bits of fp32; half-up rounding) ----
__device__ __forceinline__ float bl(u32 u){ union{u32 i; float f;} c; c.i = u << 16; return c.f; }
__device__ __forceinline__ float bh(u32 u){ union{u32 i; float f;} c; c.i = u & 0xffff0000u; return c.f; }
__device__ __forceinline__ u16 f2b(float f){
  union{float f; u32 i;} c; c.f = f;
  return (u16)((c.i + 0x8000u) >> 16);
}
__device__ __forceinline__ u32 pk2(float a, float b){
  union{float f; u32 i;} x, y; x.f = a; y.f = b;
  return ((x.i + 0x8000u) >> 16) | ((y.i + 0x8000u) & 0xffff0000u);
}
__device__ __forceinline__ void acc4(float* a, uint2 xq, uint2 eq){
  a[0] += bl(xq.x) + bl(eq.x);  a[1] += bh(xq.x) + bh(eq.x);
  a[2] += bl(xq.y) + bl(eq.y);  a[3] += bh(xq.y) + bh(eq.y);
}

// =====================================================================
// k_setup: transpose weights to bf16 n-major WT[n][k], zero cnt.
// =====================================================================
__global__ __launch_bounds__(256) void k_setup(
    const float* __restrict__ Wenc, const float* __restrict__ W1,
    const float* __restrict__ W2, u16* __restrict__ WencT,
    u16* __restrict__ W1T, u16* __restrict__ W2T,
    int* __restrict__ cnt, int N)
{
  int i = blockIdx.x * 256 + threadIdx.x;
  if (i < 16384) {                        // WencT: [128 n][128 k]
    int n = i >> 7, k = i & 127;
    WencT[i] = f2b(Wenc[k * 128 + n]);
  } else if (i < 49152) {                 // W1T: [256 n][128 k]
    int j = i - 16384;
    int n = j >> 7, k = j & 127;
    W1T[j] = f2b(W1[k * 256 + n]);
  } else if (i < 81920) {                 // W2T: [128 n][256 k]
    int j = i - 49152;
    int n = j >> 8, k = j & 255;
    W2T[j] = f2b(W2[k * 128 + n]);
  } else {
    int j = i - 81920;
    if (j < N) cnt[j] = 0;
  }
}

// =====================================================================
// k_count: degree histogram. 0 LDS -> full occupancy for latency hiding.
// =====================================================================
__global__ __launch_bounds__(256) void k_count(
    const int* __restrict__ ei, int* __restrict__ cnt, int E)
{
  int e = blockIdx.x * 256 + threadIdx.x;
  if (e < E) atomicAdd(&cnt[ei[E + e]], 1);
}

// =====================================================================
// k_scan_block: per-1024-chunk exclusive scan of cnt -> offs, + bsum.
// =====================================================================
__global__ __launch_bounds__(256) void k_scan_block(
    const int* __restrict__ cnt, int* __restrict__ offs,
    int* __restrict__ bsum, int n)
{
  __shared__ int sS[256];
  const int b = blockIdx.x, t = threadIdx.x;
  const int i0 = b * 1024 + t * 4;
  int4 v = make_int4(0, 0, 0, 0);
  if (i0 + 3 < n) v = *(const int4*)&cnt[i0];
  else {
    if (i0     < n) v.x = cnt[i0];
    if (i0 + 1 < n) v.y = cnt[i0 + 1];
    if (i0 + 2 < n) v.z = cnt[i0 + 2];
  }
  int s = v.x + v.y + v.z + v.w;
  sS[t] = s;
  __syncthreads();
  for (int d = 1; d < 256; d <<= 1) {
    int val = (t >= d) ? sS[t - d] : 0;
    __syncthreads();
    sS[t] += val;
    __syncthreads();
  }
  int ex = sS[t] - s;
  if (t == 255) bsum[b] = sS[t];
  int o0 = ex, o1 = o0 + v.x, o2 = o1 + v.y, o3 = o2 + v.z;
  if (i0     < n) offs[i0]     = o0;
  if (i0 + 1 < n) offs[i0 + 1] = o1;
  if (i0 + 2 < n) offs[i0 + 2] = o2;
  if (i0 + 3 < n) offs[i0 + 3] = o3;
}

// =====================================================================
// k_scan_add: add bsum prefix (inline, nb small) -> offs, cursor.
// =====================================================================
__global__ __launch_bounds__(256) void k_scan_add(
    int* __restrict__ offs, int* __restrict__ cursor,
    const int* __restrict__ bsum, int nb, int n, int E)
{
  __shared__ int sOff;
  const int t = threadIdx.x;
  const int i = blockIdx.x * 256 + t;
  const int myb = (blockIdx.x * 256) >> 10;
  if (t == 0) {
    int s = 0;
    for (int j = 0; j < myb; j++) s += bsum[j];
    sOff = s;
  }
  __syncthreads();
  if (i < n) {
    int v = offs[i] + sOff;
    offs[i] = v;
    cursor[i] = v;
  }
  if (i == n) offs[n] = E;
}

// =====================================================================
// k_encfill: blocks [0, fillBlocks)  -> scatter packed edge records
//            blocks [fillBlocks, ..) -> xenc = bf16(PReLU(x) @ W_enc)
// Fill is latency-bound (random 4B writes, 16x line amplification);
// enc is MFMA-bound. Co-resident on the same CUs they overlap.
// =====================================================================
__global__ __launch_bounds__(256) void k_encfill(
    const float* __restrict__ x, const float* __restrict__ pa,
    const u16* __restrict__ WT, u16* __restrict__ xenc, int N,
    const int* __restrict__ ei, const int* __restrict__ ea,
    int* __restrict__ cursor, u32* __restrict__ recs, int E, int fillBlocks)
{
  if ((int)blockIdx.x < fillBlocks) {
    int e = blockIdx.x * 256 + threadIdx.x;
    if (e >= E) return;
    int src = ei[e];
    int dst = ei[E + e];
    int2 a = *(const int2*)&ea[2 * e];
    int pos = atomicAdd(&cursor[dst], 1);
    recs[pos] = (u32)src | ((u32)(a.x * 6 + a.y) << 26);
    return;
  }

  const int K = 128, SK = 136, NT = 8;
  __shared__ u16 sB[128 * SK];           // 34 KB

  const int t = threadIdx.x;
  #pragma unroll
  for (int j = 0; j < 8; j++) {
    int i = t + 256 * j;
    int n = i >> 4, k8 = i & 15;
    *(uint4*)&sB[n * SK + k8 * 8] = *(const uint4*)&WT[n * K + k8 * 8];
  }
  __syncthreads();

  const float slope = pa[0];
  const int lane = t & 63, wave = t >> 6, quad = lane >> 4, l16 = lane & 15;
  const int m0 = ((int)blockIdx.x - fillBlocks) * 128 + wave * 32;
  if (m0 >= N) return;

  f32x4 acc[2][NT];
  #pragma unroll
  for (int mr = 0; mr < 2; mr++)
    #pragma unroll
    for (int nt = 0; nt < NT; nt++) acc[mr][nt] = (f32x4){0.f, 0.f, 0.f, 0.f};

  #pragma unroll
  for (int ks = 0; ks < 4; ks++) {
    const int k0 = ks * 32 + quad * 8;
    union { u32 u[4]; short8 s; } a[2];
    #pragma unroll
    for (int mr = 0; mr < 2; mr++) {
      int row = m0 + mr * 16 + l16; row = min(row, N - 1);
      const float4* ap = (const float4*)&x[(size_t)row * 128 + k0];
      float4 f0 = ap[0], f1 = ap[1];
      float v0 = f0.x > 0.f ? f0.x : slope * f0.x;
      float v1 = f0.y > 0.f ? f0.y : slope * f0.y;
      float v2 = f0.z > 0.f ? f0.z : slope * f0.z;
      float v3 = f0.w > 0.f ? f0.w : slope * f0.w;
      float v4 = f1.x > 0.f ? f1.x : slope * f1.x;
      float v5 = f1.y > 0.f ? f1.y : slope * f1.y;
      float v6 = f1.z > 0.f ? f1.z : slope * f1.z;
      float v7 = f1.w > 0.f ? f1.w : slope * f1.w;
      a[mr].u[0] = pk2(v0, v1); a[mr].u[1] = pk2(v2, v3);
      a[mr].u[2] = pk2(v4, v5); a[mr].u[3] = pk2(v6, v7);
    }
    #pragma unroll
    for (int nt = 0; nt < NT; nt++) {
      short8 b = *(const short8*)&sB[(nt * 16 + l16) * SK + k0];
      acc[0][nt] = __builtin_amdgcn_mfma_f32_16x16x32_bf16(a[0].s, b, acc[0][nt], 0, 0, 0);
      acc[1][nt] = __builtin_amdgcn_mfma_f32_16x16x32_bf16(a[1].s, b, acc[1][nt], 0, 0, 0);
    }
  }

  #pragma unroll
  for (int mr = 0; mr < 2; mr++)
    #pragma unroll
    for (int nt = 0; nt < NT; nt++) {
      int col = nt * 16 + l16;
      #pragma unroll
      for (int r = 0; r < 4; r++) {
        int row = m0 + mr * 16 + quad * 4 + r;
        if (row < N) xenc[(size_t)row * 128 + col] = f2b(acc[mr][nt][r]);
      }
    }
}

// =====================================================================
// k_gather: one wave per node, 2 edges concurrently (32 lanes/edge,
// dwordx2/lane), pair-loop unrolled x4 => 8 edge-loads in flight/wave.
// =====================================================================
__global__ __launch_bounds__(256) void k_gather(
    const int* __restrict__ offs, const u32* __restrict__ recs,
    const float* __restrict__ e1, const float* __restrict__ e2,
    const u32* __restrict__ xenc32, u32* __restrict__ aggb, int N)
{
  __shared__ u32 sE[36 * 64];   // 9.2 KB, packed bf16 pairs

  const int t = threadIdx.x;
  for (int i = t; i < 36 * 64; i += 256) {
    int comb = i >> 6, l = i & 63;
    int c1 = comb / 6, c2 = comb - c1 * 6;
    float2 v1 = *(const float2*)&e1[c1 * 128 + 2 * l];
    float2 v2 = *(const float2*)&e2[c2 * 128 + 2 * l];
    sE[i] = pk2(v1.x + v2.x, v1.y + v2.y);
  }
  __syncthreads();

  const int v = blockIdx.x * 4 + (t >> 6);
  if (v >= N) return;
  const int lane = t & 63, g = lane >> 5, sub = lane & 31;
  const u32 M = 0x3ffffffu;

  float a[4];
  #pragma unroll
  for (int j = 0; j < 4; j++) a[j] = 0.f;

  if (g == 0) {                           // self-loop (combo 5*6+0=30)
    uint2 xq = *(const uint2*)&xenc32[(size_t)v * 64 + sub * 2];
    uint2 eq = *(const uint2*)&sE[30 * 64 + sub * 2];
    acc4(a, xq, eq);
  }

  const int beg = offs[v], end = offs[v + 1];
  for (int base = beg; base < end; base += 64) {
    u32 rv = 0;
    if (base + lane < end) rv = recs[base + lane];
    const int cnt = min(64, end - base);
    const int npair = cnt >> 1;
    int jj = 0;
    for (; jj + 4 <= npair; jj += 4) {
      u32 r0 = __shfl(rv, (jj + 0) * 2 + g);
      u32 r1 = __shfl(rv, (jj + 1) * 2 + g);
      u32 r2 = __shfl(rv, (jj + 2) * 2 + g);
      u32 r3 = __shfl(rv, (jj + 3) * 2 + g);
      uint2 x0 = *(const uint2*)&xenc32[(size_t)(r0 & M) * 64 + sub * 2];
      uint2 x1 = *(const uint2*)&xenc32[(size_t)(r1 & M) * 64 + sub * 2];
      uint2 x2 = *(const uint2*)&xenc32[(size_t)(r2 & M) * 64 + sub * 2];
      uint2 x3 = *(const uint2*)&xenc32[(size_t)(r3 & M) * 64 + sub * 2];
      uint2 e0 = *(const uint2*)&sE[(r0 >> 26) * 64 + sub * 2];
      uint2 e1q = *(const uint2*)&sE[(r1 >> 26) * 64 + sub * 2];
      uint2 e2q = *(const uint2*)&sE[(r2 >> 26) * 64 + sub * 2];
      uint2 e3q = *(const uint2*)&sE[(r3 >> 26) * 64 + sub * 2];
      acc4(a, x0, e0); acc4(a, x1, e1q); acc4(a, x2, e2q); acc4(a, x3, e3q);
    }
    for (; jj < npair; jj++) {
      u32 r = __shfl(rv, jj * 2 + g);
      uint2 xq = *(const uint2*)&xenc32[(size_t)(r & M) * 64 + sub * 2];
      uint2 eq = *(const uint2*)&sE[(r >> 26) * 64 + sub * 2];
      acc4(a, xq, eq);
    }
    if (cnt & 1) {                        // odd tail: group 0 handles it
      u32 r = __shfl(rv, cnt - 1);
      if (g == 0) {
        uint2 xq = *(const uint2*)&xenc32[(size_t)(r & M) * 64 + sub * 2];
        uint2 eq = *(const uint2*)&sE[(r >> 26) * 64 + sub * 2];
        acc4(a, xq, eq);
      }
    }
  }

  #pragma unroll
  for (int j = 0; j < 4; j++) a[j] += __shfl_xor(a[j], 32);

  if (g == 0) {
    uint2 o;
    o.x = pk2(a[0], a[1]);
    o.y = pk2(a[2], a[3]);
    *(uint2*)&aggb[(size_t)v * 64 + sub * 2] = o;
  }
}

// =====================================================================
// k_mlp (fused): out = silu(agg @ W1 + b1) @ W2 + b2
// =====================================================================
__global__ __launch_bounds__(256) void k_mlp(
    const u16* __restrict__ aggb, const u16* __restrict__ W1T,
    const float* __restrict__ b1, const u16* __restrict__ W2T,
    const float* __restrict__ b2, float* __restrict__ out, int N)
{
  const int SK = 136;
  __shared__ u16 sW1[128 * SK];     // 34 KB: W1 n-half (h cols), all k
  __shared__ u16 sW2[128 * SK];     // 34 KB: W2 all n, k-half
  __shared__ u16 sH [128 * SK];     // 34 KB: h tile (128 rows x 128 cols)
  __shared__ float sB1[256];
  __shared__ float sB2[128];

  const int t = threadIdx.x;
  const int lane = t & 63, wave = t >> 6, quad = lane >> 4, l16 = lane & 15;
  const int m0 = blockIdx.x * 128 + wave * 32;

  if (t < 128) sB2[t] = b2[t];
  sB1[t] = b1[t];

  union { uint4 q; short8 s; } a[2][4];
  #pragma unroll
  for (int mr = 0; mr < 2; mr++) {
    int row = min(m0 + mr * 16 + l16, N - 1);
    #pragma unroll
    for (int ks = 0; ks < 4; ks++)
      a[mr][ks].q = *(const uint4*)&aggb[(size_t)row * 128 + ks * 32 + quad * 8];
  }

  f32x4 acc2[2][8];
  #pragma unroll
  for (int mr = 0; mr < 2; mr++)
    #pragma unroll
    for (int nt = 0; nt < 8; nt++) acc2[mr][nt] = (f32x4){0.f, 0.f, 0.f, 0.f};

  for (int half = 0; half < 2; half++) {
    #pragma unroll
    for (int j = 0; j < 8; j++) {
      int i = t + 256 * j;
      int n = i >> 4, k8 = i & 15;
      *(uint4*)&sW1[n * SK + k8 * 8] =
          *(const uint4*)&W1T[(size_t)(half * 128 + n) * 128 + k8 * 8];
      *(uint4*)&sW2[n * SK + k8 * 8] =
          *(const uint4*)&W2T[(size_t)n * 256 + half * 128 + k8 * 8];
    }
    __syncthreads();

    f32x4 acc1[2][8];
    #pragma unroll
    for (int mr = 0; mr < 2; mr++)
      #pragma unroll
      for (int nt = 0; nt < 8; nt++) acc1[mr][nt] = (f32x4){0.f, 0.f, 0.f, 0.f};

    #pragma unroll
    for (int ks = 0; ks < 4; ks++) {
      const int k0 = ks * 32 + quad * 8;
      #pragma unroll
      for (int nt = 0; nt < 8; nt++) {
        short8 b = *(const short8*)&sW1[(nt * 16 + l16) * SK + k0];
        acc1[0][nt] = __builtin_amdgcn_mfma_f32_16x16x32_bf16(a[0][ks].s, b, acc1[0][nt], 0, 0, 0);
        acc1[1][nt] = __builtin_amdgcn_mfma_f32_16x16x32_bf16(a[1][ks].s, b, acc1[1][nt], 0, 0, 0);
      }
    }

    #pragma unroll
    for (int mr = 0; mr < 2; mr++)
      #pragma unroll
      for (int nt = 0; nt < 8; nt++) {
        int col = nt * 16 + l16;
        float bias = sB1[half * 128 + col];
        #pragma unroll
        for (int r = 0; r < 4; r++) {
          float z = acc1[mr][nt][r] + bias;
          float s = z / (1.f + __expf(-z));
          sH[(wave * 32 + mr * 16 + quad * 4 + r) * SK + col] = f2b(s);
        }
      }
    __syncthreads();

    #pragma unroll
    for (int ks = 0; ks < 4; ks++) {
      const int k0 = ks * 32 + quad * 8;
      union { uint4 q; short8 s; } ah[2];
      #pragma unroll
      for (int mr = 0; mr < 2; mr++)
        ah[mr].q = *(const uint4*)&sH[(wave * 32 + mr * 16 + l16) * SK + k0];
      #pragma unroll
      for (int nt = 0; nt < 8; nt++) {
        short8 b = *(const short8*)&sW2[(nt * 16 + l16) * SK + k0];
        acc2[0][nt] = __builtin_amdgcn_mfma_f32_16x16x32_bf16(ah[0].s, b, acc2[0][nt], 0, 0, 0);
        acc2[1][nt] = __builtin_amdgcn_mfma_f32_16x16x32_bf16(ah[1].s, b, acc2[1][nt], 0, 0, 0);
      }
    }
    __syncthreads();
  }

  #pragma unroll
  for (int mr = 0; mr < 2; mr++)
    #pragma unroll
    for (int nt = 0; nt < 8; nt++) {
      int col = nt * 16 + l16;
      float bias = sB2[col];
      #pragma unroll
      for (int r = 0; r < 4; r++) {
        int row = m0 + mr * 16 + quad * 4 + r;
        if (row < N) out[(size_t)row * 128 + col] = acc2[mr][nt][r] + bias;
      }
    }
}

// =====================================================================
extern "C" void kernel_launch(void* const* d_in, const int* in_sizes, int n_in,
                              void* d_out, int out_size, void* d_ws, size_t ws_size,
                              hipStream_t stream) {
  const float* x    = (const float*)d_in[0];
  const int*   ei   = (const int*)d_in[1];
  const int*   ea   = (const int*)d_in[2];
  const float* pa   = (const float*)d_in[3];
  const float* Wenc = (const float*)d_in[4];
  const float* e1   = (const float*)d_in[5];
  const float* e2   = (const float*)d_in[6];
  const float* W1   = (const float*)d_in[7];
  const float* b1   = (const float*)d_in[8];
  const float* W2   = (const float*)d_in[9];
  const float* b2   = (const float*)d_in[10];
  float* out = (float*)d_out;

  const int N = in_sizes[0] / 128;
  const int E = in_sizes[1] / 2;

  char* ws = (char*)d_ws;
  size_t off = 0;
  auto alloc = [&](size_t bytes) {
    void* p = ws + off;
    off = (off + bytes + 255) & ~(size_t)255;
    return p;
  };
  u16*   xenc   = (u16*)  alloc((size_t)N * 128 * 2);
  u32*   aggb   = (u32*)  alloc((size_t)N * 64 * 4);   // bf16 agg, packed
  int*   cnt    = (int*)  alloc((size_t)N * 4);
  int*   offs   = (int*)  alloc((size_t)(N + 1) * 4);
  int*   cursor = (int*)  alloc((size_t)N * 4);
  int*   bsum   = (int*)  alloc(256 * 4);
  u32*   recs   = (u32*)  alloc((size_t)E * 4);
  u16*   WencT  = (u16*)  alloc(128 * 128 * 2);
  u16*   W1T    = (u16*)  alloc(256 * 128 * 2);
  u16*   W2T    = (u16*)  alloc(128 * 256 * 2);

  const int encBlocks   = (N + 127) / 128;
  const int fillBlocks  = (E + 255) / 256;
  const int setupBlocks = (81920 + N + 255) / 256;
  const int nb          = (N + 1023) / 1024;

  k_setup<<<setupBlocks, 256, 0, stream>>>(Wenc, W1, W2, WencT, W1T, W2T, cnt, N);
  k_count<<<fillBlocks, 256, 0, stream>>>(ei, cnt, E);
  k_scan_block<<<nb, 256, 0, stream>>>(cnt, offs, bsum, N);
  k_scan_add<<<(N + 256) / 256, 256, 0, stream>>>(offs, cursor, bsum, nb, N, E);
  k_encfill<<<fillBlocks + encBlocks, 256, 0, stream>>>(
      x, pa, WencT, xenc, N, ei, ea, cursor, recs, E, fillBlocks);
  k_gather<<<(N + 3) / 4, 256, 0, stream>>>(
      offs, recs, e1, e2, (const u32*)xenc, aggb, N);
  k_mlp<<<encBlocks, 256, 0, stream>>>(
      (const u16*)aggb, W1T, b1, W2T, b2, out, N);
}

// Round 10
// 238.894 us; speedup vs baseline: 1.2679x; 1.2679x over previous
//
#include <hip/hip_runtime.h>

typedef unsigned short u16;
typedef unsigned int   u32;
typedef __attribute__((ext_vector_type(8))) short short8;   // 8 bf16 (4 VGPRs)
typedef __attribute__((ext_vector_type(4))) float f32x4;    // MFMA C/D

// ---- bf16 helpers (bf16 = top 16 bits of fp32; half-up rounding) ----
__device__ __forceinline__ float bl(u32 u){ union{u32 i; float f;} c; c.i = u << 16; return c.f; }
__device__ __forceinline__ float bh(u32 u){ union{u32 i; float f;} c; c.i = u & 0xffff0000u; return c.f; }
__device__ __forceinline__ u16 f2b(float f){
  union{float f; u32 i;} c; c.f = f;
  return (u16)((c.i + 0x8000u) >> 16);
}
__device__ __forceinline__ u32 pk2(float a, float b){
  union{float f; u32 i;} x, y; x.f = a; y.f = b;
  return ((x.i + 0x8000u) >> 16) | ((y.i + 0x8000u) & 0xffff0000u);
}
__device__ __forceinline__ void acc4(float* a, uint2 xq, uint2 eq){
  a[0] += bl(xq.x) + bl(eq.x);  a[1] += bh(xq.x) + bh(eq.x);
  a[2] += bl(xq.y) + bl(eq.y);  a[3] += bh(xq.y) + bh(eq.y);
}

// =====================================================================
// k_setup: transpose weights to bf16 n-major WT[n][k], zero cnt.
// =====================================================================
__global__ __launch_bounds__(256) void k_setup(
    const float* __restrict__ Wenc, const float* __restrict__ W1,
    const float* __restrict__ W2, u16* __restrict__ WencT,
    u16* __restrict__ W1T, u16* __restrict__ W2T,
    int* __restrict__ cnt, int N)
{
  int i = blockIdx.x * 256 + threadIdx.x;
  if (i < 16384) {                        // WencT: [128 n][128 k]
    int n = i >> 7, k = i & 127;
    WencT[i] = f2b(Wenc[k * 128 + n]);
  } else if (i < 49152) {                 // W1T: [256 n][128 k]
    int j = i - 16384;
    int n = j >> 7, k = j & 127;
    W1T[j] = f2b(W1[k * 256 + n]);
  } else if (i < 81920) {                 // W2T: [128 n][256 k]
    int j = i - 49152;
    int n = j >> 8, k = j & 255;
    W2T[j] = f2b(W2[k * 128 + n]);
  } else {
    int j = i - 81920;
    if (j < N) cnt[j] = 0;
  }
}

// =====================================================================
// k_enc_count: blocks [0, encBlocks) -> xenc = bf16(PReLU(x) @ W_enc)
//              blocks [encBlocks,..) -> degree histogram + per-edge rank
// (enc FIRST so the many latency-bound count blocks hide it — r9 lesson)
// =====================================================================
__global__ __launch_bounds__(256) void k_enc_count(
    const float* __restrict__ x, const float* __restrict__ pa,
    const u16* __restrict__ WT, u16* __restrict__ xenc, int N,
    const int* __restrict__ ei, int* __restrict__ cnt,
    int* __restrict__ rank, int E, int encBlocks)
{
  if ((int)blockIdx.x >= encBlocks) {
    int e = ((int)blockIdx.x - encBlocks) * 256 + threadIdx.x;
    if (e < E) rank[e] = atomicAdd(&cnt[ei[E + e]], 1);
    return;
  }

  const int K = 128, SK = 136, NT = 8;
  __shared__ u16 sB[128 * SK];           // 34 KB

  const int t = threadIdx.x;
  #pragma unroll
  for (int j = 0; j < 8; j++) {
    int i = t + 256 * j;
    int n = i >> 4, k8 = i & 15;
    *(uint4*)&sB[n * SK + k8 * 8] = *(const uint4*)&WT[n * K + k8 * 8];
  }
  __syncthreads();

  const float slope = pa[0];
  const int lane = t & 63, wave = t >> 6, quad = lane >> 4, l16 = lane & 15;
  const int m0 = blockIdx.x * 128 + wave * 32;
  if (m0 >= N) return;

  f32x4 acc[2][NT];
  #pragma unroll
  for (int mr = 0; mr < 2; mr++)
    #pragma unroll
    for (int nt = 0; nt < NT; nt++) acc[mr][nt] = (f32x4){0.f, 0.f, 0.f, 0.f};

  #pragma unroll
  for (int ks = 0; ks < 4; ks++) {
    const int k0 = ks * 32 + quad * 8;
    union { u32 u[4]; short8 s; } a[2];
    #pragma unroll
    for (int mr = 0; mr < 2; mr++) {
      int row = m0 + mr * 16 + l16; row = min(row, N - 1);
      const float4* ap = (const float4*)&x[(size_t)row * 128 + k0];
      float4 f0 = ap[0], f1 = ap[1];
      float v0 = f0.x > 0.f ? f0.x : slope * f0.x;
      float v1 = f0.y > 0.f ? f0.y : slope * f0.y;
      float v2 = f0.z > 0.f ? f0.z : slope * f0.z;
      float v3 = f0.w > 0.f ? f0.w : slope * f0.w;
      float v4 = f1.x > 0.f ? f1.x : slope * f1.x;
      float v5 = f1.y > 0.f ? f1.y : slope * f1.y;
      float v6 = f1.z > 0.f ? f1.z : slope * f1.z;
      float v7 = f1.w > 0.f ? f1.w : slope * f1.w;
      a[mr].u[0] = pk2(v0, v1); a[mr].u[1] = pk2(v2, v3);
      a[mr].u[2] = pk2(v4, v5); a[mr].u[3] = pk2(v6, v7);
    }
    #pragma unroll
    for (int nt = 0; nt < NT; nt++) {
      short8 b = *(const short8*)&sB[(nt * 16 + l16) * SK + k0];
      acc[0][nt] = __builtin_amdgcn_mfma_f32_16x16x32_bf16(a[0].s, b, acc[0][nt], 0, 0, 0);
      acc[1][nt] = __builtin_amdgcn_mfma_f32_16x16x32_bf16(a[1].s, b, acc[1][nt], 0, 0, 0);
    }
  }

  #pragma unroll
  for (int mr = 0; mr < 2; mr++)
    #pragma unroll
    for (int nt = 0; nt < NT; nt++) {
      int col = nt * 16 + l16;
      #pragma unroll
      for (int r = 0; r < 4; r++) {
        int row = m0 + mr * 16 + quad * 4 + r;
        if (row < N) xenc[(size_t)row * 128 + col] = f2b(acc[mr][nt][r]);
      }
    }
}

// =====================================================================
// k_scan_block: per-1024-chunk exclusive scan of cnt -> offs, + bsum.
// =====================================================================
__global__ __launch_bounds__(256) void k_scan_block(
    const int* __restrict__ cnt, int* __restrict__ offs,
    int* __restrict__ bsum, int n)
{
  __shared__ int sS[256];
  const int b = blockIdx.x, t = threadIdx.x;
  const int i0 = b * 1024 + t * 4;
  int4 v = make_int4(0, 0, 0, 0);
  if (i0 + 3 < n) v = *(const int4*)&cnt[i0];
  else {
    if (i0     < n) v.x = cnt[i0];
    if (i0 + 1 < n) v.y = cnt[i0 + 1];
    if (i0 + 2 < n) v.z = cnt[i0 + 2];
  }
  int s = v.x + v.y + v.z + v.w;
  sS[t] = s;
  __syncthreads();
  for (int d = 1; d < 256; d <<= 1) {
    int val = (t >= d) ? sS[t - d] : 0;
    __syncthreads();
    sS[t] += val;
    __syncthreads();
  }
  int ex = sS[t] - s;
  if (t == 255) bsum[b] = sS[t];
  int o0 = ex, o1 = o0 + v.x, o2 = o1 + v.y, o3 = o2 + v.z;
  if (i0     < n) offs[i0]     = o0;
  if (i0 + 1 < n) offs[i0 + 1] = o1;
  if (i0 + 2 < n) offs[i0 + 2] = o2;
  if (i0 + 3 < n) offs[i0 + 3] = o3;
}

// =====================================================================
// k_scan_add: add bsum prefix (inline, nb small) -> offs.
// =====================================================================
__global__ __launch_bounds__(256) void k_scan_add(
    int* __restrict__ offs, const int* __restrict__ bsum,
    int nb, int n, int E)
{
  __shared__ int sOff;
  const int t = threadIdx.x;
  const int i = blockIdx.x * 256 + t;
  const int myb = (blockIdx.x * 256) >> 10;
  if (t == 0) {
    int s = 0;
    for (int j = 0; j < myb; j++) s += bsum[j];
    sOff = s;
  }
  __syncthreads();
  if (i < n) offs[i] += sOff;
  if (i == n) offs[n] = E;
}

// =====================================================================
// k_fill: atomic-free scatter of packed edge records (uses rank).
// rec = src | (a1*6+a2) << 26
// =====================================================================
__global__ __launch_bounds__(256) void k_fill(
    const int* __restrict__ ei, const int* __restrict__ ea,
    const int* __restrict__ offs, const int* __restrict__ rank,
    u32* __restrict__ recs, int E)
{
  int e = blockIdx.x * 256 + threadIdx.x;
  if (e >= E) return;
  int src = ei[e];
  int dst = ei[E + e];
  int2 a = *(const int2*)&ea[2 * e];
  int pos = offs[dst] + rank[e];
  recs[pos] = (u32)src | ((u32)(a.x * 6 + a.y) << 26);
}

// =====================================================================
// k_gather: one wave per node, 2 edges concurrently (32 lanes/edge,
// dwordx2/lane), pair-loop unrolled x4 => 8 edge-loads in flight/wave.
// =====================================================================
__global__ __launch_bounds__(256) void k_gather(
    const int* __restrict__ offs, const u32* __restrict__ recs,
    const float* __restrict__ e1, const float* __restrict__ e2,
    const u32* __restrict__ xenc32, u32* __restrict__ aggb, int N)
{
  __shared__ u32 sE[36 * 64];   // 9.2 KB, packed bf16 pairs

  const int t = threadIdx.x;
  for (int i = t; i < 36 * 64; i += 256) {
    int comb = i >> 6, l = i & 63;
    int c1 = comb / 6, c2 = comb - c1 * 6;
    float2 v1 = *(const float2*)&e1[c1 * 128 + 2 * l];
    float2 v2 = *(const float2*)&e2[c2 * 128 + 2 * l];
    sE[i] = pk2(v1.x + v2.x, v1.y + v2.y);
  }
  __syncthreads();

  const int v = blockIdx.x * 4 + (t >> 6);
  if (v >= N) return;
  const int lane = t & 63, g = lane >> 5, sub = lane & 31;
  const u32 M = 0x3ffffffu;

  float a[4];
  #pragma unroll
  for (int j = 0; j < 4; j++) a[j] = 0.f;

  if (g == 0) {                           // self-loop (combo 5*6+0=30)
    uint2 xq = *(const uint2*)&xenc32[(size_t)v * 64 + sub * 2];
    uint2 eq = *(const uint2*)&sE[30 * 64 + sub * 2];
    acc4(a, xq, eq);
  }

  const int beg = offs[v], end = offs[v + 1];
  for (int base = beg; base < end; base += 64) {
    u32 rv = 0;
    if (base + lane < end) rv = recs[base + lane];
    const int cnt = min(64, end - base);
    const int npair = cnt >> 1;
    int jj = 0;
    for (; jj + 4 <= npair; jj += 4) {
      u32 r0 = __shfl(rv, (jj + 0) * 2 + g);
      u32 r1 = __shfl(rv, (jj + 1) * 2 + g);
      u32 r2 = __shfl(rv, (jj + 2) * 2 + g);
      u32 r3 = __shfl(rv, (jj + 3) * 2 + g);
      uint2 x0 = *(const uint2*)&xenc32[(size_t)(r0 & M) * 64 + sub * 2];
      uint2 x1 = *(const uint2*)&xenc32[(size_t)(r1 & M) * 64 + sub * 2];
      uint2 x2 = *(const uint2*)&xenc32[(size_t)(r2 & M) * 64 + sub * 2];
      uint2 x3 = *(const uint2*)&xenc32[(size_t)(r3 & M) * 64 + sub * 2];
      uint2 e0 = *(const uint2*)&sE[(r0 >> 26) * 64 + sub * 2];
      uint2 e1q = *(const uint2*)&sE[(r1 >> 26) * 64 + sub * 2];
      uint2 e2q = *(const uint2*)&sE[(r2 >> 26) * 64 + sub * 2];
      uint2 e3q = *(const uint2*)&sE[(r3 >> 26) * 64 + sub * 2];
      acc4(a, x0, e0); acc4(a, x1, e1q); acc4(a, x2, e2q); acc4(a, x3, e3q);
    }
    for (; jj < npair; jj++) {
      u32 r = __shfl(rv, jj * 2 + g);
      uint2 xq = *(const uint2*)&xenc32[(size_t)(r & M) * 64 + sub * 2];
      uint2 eq = *(const uint2*)&sE[(r >> 26) * 64 + sub * 2];
      acc4(a, xq, eq);
    }
    if (cnt & 1) {                        // odd tail: group 0 handles it
      u32 r = __shfl(rv, cnt - 1);
      if (g == 0) {
        uint2 xq = *(const uint2*)&xenc32[(size_t)(r & M) * 64 + sub * 2];
        uint2 eq = *(const uint2*)&sE[(r >> 26) * 64 + sub * 2];
        acc4(a, xq, eq);
      }
    }
  }

  #pragma unroll
  for (int j = 0; j < 4; j++) a[j] += __shfl_xor(a[j], 32);

  if (g == 0) {
    uint2 o;
    o.x = pk2(a[0], a[1]);
    o.y = pk2(a[2], a[3]);
    *(uint2*)&aggb[(size_t)v * 64 + sub * 2] = o;
  }
}

// =====================================================================
// k_mlp (fused): out = silu(agg @ W1 + b1) @ W2 + b2
// 128 rows/block. W1-half and W2-half share ONE LDS buffer (re-staged
// after GEMM1) -> ~71 KB LDS -> 2 blocks/CU (was 1 at 104 KB).
// =====================================================================
__global__ __launch_bounds__(256) void k_mlp(
    const u16* __restrict__ aggb, const u16* __restrict__ W1T,
    const float* __restrict__ b1, const u16* __restrict__ W2T,
    const float* __restrict__ b2, float* __restrict__ out, int N)
{
  const int SK = 136;
  __shared__ u16 sW[128 * SK];      // 34 KB: W1 n-half, then W2 k-half
  __shared__ u16 sH[128 * SK];      // 34 KB: h tile (128 rows x 128 cols)
  __shared__ float sB1[256];
  __shared__ float sB2[128];

  const int t = threadIdx.x;
  const int lane = t & 63, wave = t >> 6, quad = lane >> 4, l16 = lane & 15;
  const int m0 = blockIdx.x * 128 + wave * 32;

  if (t < 128) sB2[t] = b2[t];
  sB1[t] = b1[t];

  // A fragments (aggb rows) loaded once, reused across both halves
  union { uint4 q; short8 s; } a[2][4];
  #pragma unroll
  for (int mr = 0; mr < 2; mr++) {
    int row = min(m0 + mr * 16 + l16, N - 1);
    #pragma unroll
    for (int ks = 0; ks < 4; ks++)
      a[mr][ks].q = *(const uint4*)&aggb[(size_t)row * 128 + ks * 32 + quad * 8];
  }

  f32x4 acc2[2][8];
  #pragma unroll
  for (int mr = 0; mr < 2; mr++)
    #pragma unroll
    for (int nt = 0; nt < 8; nt++) acc2[mr][nt] = (f32x4){0.f, 0.f, 0.f, 0.f};

  for (int half = 0; half < 2; half++) {
    // stage W1 n-half
    #pragma unroll
    for (int j = 0; j < 8; j++) {
      int i = t + 256 * j;
      int n = i >> 4, k8 = i & 15;
      *(uint4*)&sW[n * SK + k8 * 8] =
          *(const uint4*)&W1T[(size_t)(half * 128 + n) * 128 + k8 * 8];
    }
    __syncthreads();

    // GEMM1: h_half = agg @ W1half
    f32x4 acc1[2][8];
    #pragma unroll
    for (int mr = 0; mr < 2; mr++)
      #pragma unroll
      for (int nt = 0; nt < 8; nt++) acc1[mr][nt] = (f32x4){0.f, 0.f, 0.f, 0.f};

    #pragma unroll
    for (int ks = 0; ks < 4; ks++) {
      const int k0 = ks * 32 + quad * 8;
      #pragma unroll
      for (int nt = 0; nt < 8; nt++) {
        short8 b = *(const short8*)&sW[(nt * 16 + l16) * SK + k0];
        acc1[0][nt] = __builtin_amdgcn_mfma_f32_16x16x32_bf16(a[0][ks].s, b, acc1[0][nt], 0, 0, 0);
        acc1[1][nt] = __builtin_amdgcn_mfma_f32_16x16x32_bf16(a[1][ks].s, b, acc1[1][nt], 0, 0, 0);
      }
    }

    // silu + C-layout -> A-layout via LDS tile (wave-local rows)
    #pragma unroll
    for (int mr = 0; mr < 2; mr++)
      #pragma unroll
      for (int nt = 0; nt < 8; nt++) {
        int col = nt * 16 + l16;
        float bias = sB1[half * 128 + col];
        #pragma unroll
        for (int r = 0; r < 4; r++) {
          float z = acc1[mr][nt][r] + bias;
          float s = z / (1.f + __expf(-z));
          sH[(wave * 32 + mr * 16 + quad * 4 + r) * SK + col] = f2b(s);
        }
      }
    __syncthreads();          // all waves done reading sW (GEMM1)

    // re-stage sW with W2 k-half
    #pragma unroll
    for (int j = 0; j < 8; j++) {
      int i = t + 256 * j;
      int n = i >> 4, k8 = i & 15;
      *(uint4*)&sW[n * SK + k8 * 8] =
          *(const uint4*)&W2T[(size_t)n * 256 + half * 128 + k8 * 8];
    }
    __syncthreads();

    // GEMM2: out_acc += h_half @ W2_khalf
    #pragma unroll
    for (int ks = 0; ks < 4; ks++) {
      const int k0 = ks * 32 + quad * 8;
      union { uint4 q; short8 s; } ah[2];
      #pragma unroll
      for (int mr = 0; mr < 2; mr++)
        ah[mr].q = *(const uint4*)&sH[(wave * 32 + mr * 16 + l16) * SK + k0];
      #pragma unroll
      for (int nt = 0; nt < 8; nt++) {
        short8 b = *(const short8*)&sW[(nt * 16 + l16) * SK + k0];
        acc2[0][nt] = __builtin_amdgcn_mfma_f32_16x16x32_bf16(ah[0].s, b, acc2[0][nt], 0, 0, 0);
        acc2[1][nt] = __builtin_amdgcn_mfma_f32_16x16x32_bf16(ah[1].s, b, acc2[1][nt], 0, 0, 0);
      }
    }
    __syncthreads();          // all waves done reading sW before next half
  }

  #pragma unroll
  for (int mr = 0; mr < 2; mr++)
    #pragma unroll
    for (int nt = 0; nt < 8; nt++) {
      int col = nt * 16 + l16;
      float bias = sB2[col];
      #pragma unroll
      for (int r = 0; r < 4; r++) {
        int row = m0 + mr * 16 + quad * 4 + r;
        if (row < N) out[(size_t)row * 128 + col] = acc2[mr][nt][r] + bias;
      }
    }
}

// =====================================================================
extern "C" void kernel_launch(void* const* d_in, const int* in_sizes, int n_in,
                              void* d_out, int out_size, void* d_ws, size_t ws_size,
                              hipStream_t stream) {
  const float* x    = (const float*)d_in[0];
  const int*   ei   = (const int*)d_in[1];
  const int*   ea   = (const int*)d_in[2];
  const float* pa   = (const float*)d_in[3];
  const float* Wenc = (const float*)d_in[4];
  const float* e1   = (const float*)d_in[5];
  const float* e2   = (const float*)d_in[6];
  const float* W1   = (const float*)d_in[7];
  const float* b1   = (const float*)d_in[8];
  const float* W2   = (const float*)d_in[9];
  const float* b2   = (const float*)d_in[10];
  float* out = (float*)d_out;

  const int N = in_sizes[0] / 128;
  const int E = in_sizes[1] / 2;

  char* ws = (char*)d_ws;
  size_t off = 0;
  auto alloc = [&](size_t bytes) {
    void* p = ws + off;
    off = (off + bytes + 255) & ~(size_t)255;
    return p;
  };
  u16*   xenc   = (u16*)  alloc((size_t)N * 128 * 2);
  u32*   aggb   = (u32*)  alloc((size_t)N * 64 * 4);   // bf16 agg, packed
  int*   cnt    = (int*)  alloc((size_t)N * 4);
  int*   offs   = (int*)  alloc((size_t)(N + 1) * 4);
  int*   rank   = (int*)  alloc((size_t)E * 4);
  int*   bsum   = (int*)  alloc(256 * 4);
  u32*   recs   = (u32*)  alloc((size_t)E * 4);
  u16*   WencT  = (u16*)  alloc(128 * 128 * 2);
  u16*   W1T    = (u16*)  alloc(256 * 128 * 2);
  u16*   W2T    = (u16*)  alloc(128 * 256 * 2);

  const int encBlocks   = (N + 127) / 128;
  const int edgeBlocks  = (E + 255) / 256;
  const int setupBlocks = (81920 + N + 255) / 256;
  const int nb          = (N + 1023) / 1024;

  k_setup<<<setupBlocks, 256, 0, stream>>>(Wenc, W1, W2, WencT, W1T, W2T, cnt, N);
  k_enc_count<<<encBlocks + edgeBlocks, 256, 0, stream>>>(
      x, pa, WencT, xenc, N, ei, cnt, rank, E, encBlocks);
  k_scan_block<<<nb, 256, 0, stream>>>(cnt, offs, bsum, N);
  k_scan_add<<<(N + 256) / 256, 256, 0, stream>>>(offs, bsum, nb, N, E);
  k_fill<<<edgeBlocks, 256, 0, stream>>>(ei, ea, offs, rank, recs, E);
  k_gather<<<(N + 3) / 4, 256, 0, stream>>>(
      offs, recs, e1, e2, (const u32*)xenc, aggb, N);
  k_mlp<<<encBlocks, 256, 0, stream>>>(
      (const u16*)aggb, W1T, b1, W2T, b2, out, N);
}